// Round 1
// baseline (202.085 us; speedup 1.0000x reference)
//
#include <hip/hip_runtime.h>
#include <math.h>

#define EPSF 1e-7f
// 1 - SIGMA - ln(1 - SIGMA) with SIGMA = 0.5
#define REP_DENOM 1.19314718055994530942f

__device__ __forceinline__ float iou_pp(float ax0, float ay0, float ax1, float ay1, float aarea,
                                        float bx0, float by0, float bx1, float by1, float barea) {
    float lx = fmaxf(ax0, bx0), ly = fmaxf(ay0, by0);
    float rx = fminf(ax1, bx1), ry = fminf(ay1, by1);
    float w = fmaxf(rx - lx + 1.0f, 0.0f);
    float h = fmaxf(ry - ly + 1.0f, 0.0f);
    float ov = w * h;
    float denom = fmaxf(aarea + barea - ov, EPSF);
    float v = ov / denom;
    return fminf(fmaxf(v, EPSF), 1.0f);
}

__device__ __forceinline__ float rep_term_fast(float v) {
    float lin = (v - 0.5f) * (1.0f / REP_DENOM);
    float lg = -__logf(fmaxf(1.0f - v, EPSF));
    return (v > 0.5f) ? lin : lg;
}

// ---------------------------------------------------------------------------
// prep: xywh -> xyxy for gt and pre; per-pred +1-convention area; zero accs
// ws layout (bytes): [0) 3 doubles acc | 256) g4 M*4 f32 | g4end aligned) p5 N*5 f32
// ---------------------------------------------------------------------------
__global__ __launch_bounds__(256) void prep_kernel(
    const float* __restrict__ gt, const float* __restrict__ pre,
    float* __restrict__ g4, float* __restrict__ p5, double* __restrict__ acc,
    int M, int N)
{
    int i = blockIdx.x * 256 + threadIdx.x;
    if (i < 3) acc[i] = 0.0;
    if (i < M) {
        float x = gt[i * 4 + 0], y = gt[i * 4 + 1], w = gt[i * 4 + 2], h = gt[i * 4 + 3];
        g4[i * 4 + 0] = x - w / 2.0f;
        g4[i * 4 + 1] = y - h / 2.0f;
        g4[i * 4 + 2] = x + w / 2.0f;
        g4[i * 4 + 3] = y + h / 2.0f;
    }
    if (i < N) {
        float x = pre[i * 4 + 0], y = pre[i * 4 + 1], w = pre[i * 4 + 2], h = pre[i * 4 + 3];
        float x0 = x - w / 2.0f, y0 = y - h / 2.0f;
        float x1 = x + w / 2.0f, y1 = y + h / 2.0f;
        p5[i * 5 + 0] = x0;
        p5[i * 5 + 1] = y0;
        p5[i * 5 + 2] = x1;
        p5[i * 5 + 3] = y1;
        p5[i * 5 + 4] = (x1 - x0 + 1.0f) * (y1 - y0 + 1.0f);
    }
}

// ---------------------------------------------------------------------------
// attr + repgt: one thread per prediction; gt boxes staged in LDS.
// Pass 1: argmax IoU over gts (strict >, first occurrence == jnp.argmax).
// Pass 2: argmax skipping idx1 (== argmax after scatter-zero of idx1 entry).
// ---------------------------------------------------------------------------
__global__ __launch_bounds__(256) void attr_repgt_kernel(
    const float* __restrict__ g4, const float* __restrict__ p5,
    double* __restrict__ acc, int M, int N)
{
    __shared__ float gs[512 * 4];
    __shared__ double red[8];
    int t = threadIdx.x;
    for (int k = t; k < M * 4; k += 256) gs[k] = g4[k];
    __syncthreads();

    int n = blockIdx.x * 256 + t;
    bool active = (n < N);
    int nc = active ? n : (N - 1);

    float px0 = p5[nc * 5 + 0], py0 = p5[nc * 5 + 1];
    float px1 = p5[nc * 5 + 2], py1 = p5[nc * 5 + 3];
    float pa  = p5[nc * 5 + 4];

    float best1 = -1.0f; int idx1 = 0;
    for (int m = 0; m < M; ++m) {
        float gx0 = gs[m * 4 + 0], gy0 = gs[m * 4 + 1];
        float gx1 = gs[m * 4 + 2], gy1 = gs[m * 4 + 3];
        float ga = (gx1 - gx0 + 1.0f) * (gy1 - gy0 + 1.0f);
        float v = iou_pp(gx0, gy0, gx1, gy1, ga, px0, py0, px1, py1, pa);
        if (v > best1) { best1 = v; idx1 = m; }
    }
    float best2 = -1.0f; int idx2 = 0;
    for (int m = 0; m < M; ++m) {
        if (m == idx1) continue;
        float gx0 = gs[m * 4 + 0], gy0 = gs[m * 4 + 1];
        float gx1 = gs[m * 4 + 2], gy1 = gs[m * 4 + 3];
        float ga = (gx1 - gx0 + 1.0f) * (gy1 - gy0 + 1.0f);
        float v = iou_pp(gx0, gy0, gx1, gy1, ga, px0, py0, px1, py1, pa);
        if (v > best2) { best2 = v; idx2 = m; }
    }

    // attr: smooth-l1 (beta=1) of pred vs g[idx1], summed over 4 coords
    float ax0 = gs[idx1 * 4 + 0], ay0 = gs[idx1 * 4 + 1];
    float ax1 = gs[idx1 * 4 + 2], ay1 = gs[idx1 * 4 + 3];
    float s = 0.0f, d;
    d = fabsf(px0 - ax0); s += (d < 1.0f) ? 0.5f * d * d : d - 0.5f;
    d = fabsf(py0 - ay0); s += (d < 1.0f) ? 0.5f * d * d : d - 0.5f;
    d = fabsf(px1 - ax1); s += (d < 1.0f) ? 0.5f * d * d : d - 0.5f;
    d = fabsf(py1 - ay1); s += (d < 1.0f) ? 0.5f * d * d : d - 0.5f;

    // repgt: IoG (no +1 convention) vs g[idx2]
    float rx0 = gs[idx2 * 4 + 0], ry0 = gs[idx2 * 4 + 1];
    float rx1 = gs[idx2 * 4 + 2], ry1 = gs[idx2 * 4 + 3];
    float lx = fmaxf(px0, rx0), ly = fmaxf(py0, ry0);
    float rx = fminf(px1, rx1), ry = fminf(py1, ry1);
    float w = fmaxf(rx - lx, 0.0f), h = fmaxf(ry - ly, 0.0f);
    float inter = w * h;
    float garea = fabsf(rx1 - rx0) * fabsf(ry1 - ry0);
    float iog = inter / garea;
    float rep;
    if (iog > 0.5f) rep = (iog - 0.5f) / REP_DENOM;
    else            rep = -logf(fmaxf(1.0f - iog, EPSF));

    if (!active) { s = 0.0f; rep = 0.0f; }

    for (int off = 32; off > 0; off >>= 1) {
        s   += __shfl_down(s, off);
        rep += __shfl_down(rep, off);
    }
    if ((t & 63) == 0) { red[t >> 6] = (double)s; red[4 + (t >> 6)] = (double)rep; }
    __syncthreads();
    if (t == 0) {
        atomicAdd(&acc[0], red[0] + red[1] + red[2] + red[3]);
        atomicAdd(&acc[1], red[4] + red[5] + red[6] + red[7]);
    }
}

// ---------------------------------------------------------------------------
// repbox: strict upper triangle of NxN proposal IoU -> rep term sum.
// 128x128 tiles; block skips if entirely below diagonal. Column box held in
// registers; row box is an LDS broadcast per inner iteration.
// ---------------------------------------------------------------------------
__global__ __launch_bounds__(256) void repbox_kernel(
    const float* __restrict__ p5, double* __restrict__ acc, int N)
{
    int bi = blockIdx.y;  // row tile
    int bj = blockIdx.x;  // col tile
    if (bi > bj) return;

    __shared__ float rowb[128 * 5];
    __shared__ float colb[128 * 5];
    __shared__ double red[4];
    int t = threadIdx.x;
    int rbase = bi * 128, cbase = bj * 128;

    for (int k = t; k < 128 * 5; k += 256) {
        int rb = rbase + k / 5;
        int cb = cbase + k / 5;
        rowb[k] = (rb < N) ? p5[rbase * 5 + k] : 0.0f;
        colb[k] = (cb < N) ? p5[cbase * 5 + k] : 0.0f;
    }
    __syncthreads();

    int c = t & 127;
    int half = t >> 7;  // 0 or 1: which 64-row stripe
    float cx0 = colb[c * 5 + 0], cy0 = colb[c * 5 + 1];
    float cx1 = colb[c * 5 + 2], cy1 = colb[c * 5 + 3];
    float ca  = colb[c * 5 + 4];
    int jg = cbase + c;

    float sum = 0.0f;
    #pragma unroll 4
    for (int rr = 0; rr < 64; ++rr) {
        int r = half * 64 + rr;
        int ig = rbase + r;
        float rx0 = rowb[r * 5 + 0], ry0 = rowb[r * 5 + 1];
        float rx1 = rowb[r * 5 + 2], ry1 = rowb[r * 5 + 3];
        float ra  = rowb[r * 5 + 4];
        float v = iou_pp(rx0, ry0, rx1, ry1, ra, cx0, cy0, cx1, cy1, ca);
        float term = rep_term_fast(v);
        if (jg > ig && jg < N && ig < N) sum += term;
    }

    for (int off = 32; off > 0; off >>= 1) sum += __shfl_down(sum, off);
    if ((t & 63) == 0) red[t >> 6] = (double)sum;
    __syncthreads();
    if (t == 0) atomicAdd(&acc[2], red[0] + red[1] + red[2] + red[3]);
}

__global__ void finalize_kernel(const double* __restrict__ acc,
                                float* __restrict__ out, int N, long long cnt)
{
    double attr   = acc[0] / (double)N;
    double repgt  = acc[1] / (double)N;
    double repbox = acc[2] / (double)cnt;
    out[0] = (float)(attr + 0.5 * repgt + 0.5 * repbox);
}

extern "C" void kernel_launch(void* const* d_in, const int* in_sizes, int n_in,
                              void* d_out, int out_size, void* d_ws, size_t ws_size,
                              hipStream_t stream) {
    const float* gt  = (const float*)d_in[0];
    const float* pre = (const float*)d_in[1];
    int M = in_sizes[0] / 4;   // 512
    int N = in_sizes[1] / 4;   // 8192

    char* ws = (char*)d_ws;
    double* acc = (double*)ws;
    float* g4 = (float*)(ws + 256);
    size_t g4_bytes = ((size_t)M * 4 * sizeof(float) + 255) / 256 * 256;
    float* p5 = (float*)(ws + 256 + g4_bytes);
    float* out = (float*)d_out;

    int nb = (N + 255) / 256;
    prep_kernel<<<nb, 256, 0, stream>>>(gt, pre, g4, p5, acc, M, N);
    attr_repgt_kernel<<<nb, 256, 0, stream>>>(g4, p5, acc, M, N);

    int nt = (N + 127) / 128;
    dim3 gb(nt, nt);
    repbox_kernel<<<gb, 256, 0, stream>>>(p5, acc, N);

    long long cnt = (long long)N * (N - 1) / 2;
    finalize_kernel<<<1, 1, 0, stream>>>(acc, out, N, cnt);
}

// Round 2
// 107.091 us; speedup vs baseline: 1.8870x; 1.8870x over previous
//
#include <hip/hip_runtime.h>
#include <math.h>

#define EPSF 1e-7f
// 1 - SIGMA - ln(1 - SIGMA) with SIGMA = 0.5
#define REP_DENOM 1.19314718055994530942f

__device__ __forceinline__ float iou_pp(float ax0, float ay0, float ax1, float ay1, float aarea,
                                        float bx0, float by0, float bx1, float by1, float barea) {
    float lx = fmaxf(ax0, bx0), ly = fmaxf(ay0, by0);
    float rx = fminf(ax1, bx1), ry = fminf(ay1, by1);
    float w = fmaxf(rx - lx + 1.0f, 0.0f);
    float h = fmaxf(ry - ly + 1.0f, 0.0f);
    float ov = w * h;
    float denom = fmaxf(aarea + barea - ov, EPSF);
    float v = ov / denom;   // exact division: argmax tie behavior must match ref
    return fminf(fmaxf(v, EPSF), 1.0f);
}

// ---------------------------------------------------------------------------
// prep: xywh -> xyxy; gt stored SoA [5][M] (x0,y0,x1,y1,area+1conv);
// pre stored AoS [N][5]. Zero the 3 accumulators.
// ---------------------------------------------------------------------------
__global__ __launch_bounds__(256) void prep_kernel(
    const float* __restrict__ gt, const float* __restrict__ pre,
    float* __restrict__ g5, float* __restrict__ p5, double* __restrict__ acc,
    int M, int N)
{
    int i = blockIdx.x * 256 + threadIdx.x;
    if (i < 3) acc[i] = 0.0;
    if (i < M) {
        float x = gt[i * 4 + 0], y = gt[i * 4 + 1], w = gt[i * 4 + 2], h = gt[i * 4 + 3];
        float x0 = x - w / 2.0f, y0 = y - h / 2.0f;
        float x1 = x + w / 2.0f, y1 = y + h / 2.0f;
        g5[0 * M + i] = x0;
        g5[1 * M + i] = y0;
        g5[2 * M + i] = x1;
        g5[3 * M + i] = y1;
        g5[4 * M + i] = (x1 - x0 + 1.0f) * (y1 - y0 + 1.0f);
    }
    if (i < N) {
        float x = pre[i * 4 + 0], y = pre[i * 4 + 1], w = pre[i * 4 + 2], h = pre[i * 4 + 3];
        float x0 = x - w / 2.0f, y0 = y - h / 2.0f;
        float x1 = x + w / 2.0f, y1 = y + h / 2.0f;
        p5[i * 5 + 0] = x0;
        p5[i * 5 + 1] = y0;
        p5[i * 5 + 2] = x1;
        p5[i * 5 + 3] = y1;
        p5[i * 5 + 4] = (x1 - x0 + 1.0f) * (y1 - y0 + 1.0f);
    }
}

// ---------------------------------------------------------------------------
// attr + repgt: ONE WAVE per prediction (4 waves / 256-thread block).
// Lanes split the gt scan (m = lane, lane+64, ...); butterfly argmax with
// (value, min index) tie-break == jnp.argmax first-occurrence semantics.
// Pass 2 skips idx1 (== argmax after scatter-zero, since all IoUs >= EPS > 0).
// ---------------------------------------------------------------------------
__global__ __launch_bounds__(256) void attr_repgt_kernel(
    const float* __restrict__ g5, const float* __restrict__ p5,
    double* __restrict__ acc, int M, int N)
{
    __shared__ float gs[5 * 512];
    __shared__ double red[8];
    int t = threadIdx.x;
    for (int k = t; k < 5 * M; k += 256) {
        int c = k / M, m = k - c * M;
        gs[c * 512 + m] = g5[k];
    }
    if (t < 8) red[t] = 0.0;
    __syncthreads();

    int wave = t >> 6, lane = t & 63;
    int n = blockIdx.x * 4 + wave;
    float s = 0.0f, rep = 0.0f;
    if (n < N) {
        float px0 = p5[n * 5 + 0], py0 = p5[n * 5 + 1];
        float px1 = p5[n * 5 + 2], py1 = p5[n * 5 + 3];
        float pa  = p5[n * 5 + 4];

        float best1 = -1.0f; int idx1 = 0;
        for (int m = lane; m < M; m += 64) {
            float v = iou_pp(gs[m], gs[512 + m], gs[1024 + m], gs[1536 + m], gs[2048 + m],
                             px0, py0, px1, py1, pa);
            if (v > best1) { best1 = v; idx1 = m; }
        }
        for (int off = 32; off > 0; off >>= 1) {
            float bv = __shfl_xor(best1, off);
            int   bi = __shfl_xor(idx1, off);
            if (bv > best1 || (bv == best1 && bi < idx1)) { best1 = bv; idx1 = bi; }
        }

        float best2 = -1.0f; int idx2 = 0;
        for (int m = lane; m < M; m += 64) {
            if (m == idx1) continue;
            float v = iou_pp(gs[m], gs[512 + m], gs[1024 + m], gs[1536 + m], gs[2048 + m],
                             px0, py0, px1, py1, pa);
            if (v > best2) { best2 = v; idx2 = m; }
        }
        for (int off = 32; off > 0; off >>= 1) {
            float bv = __shfl_xor(best2, off);
            int   bi = __shfl_xor(idx2, off);
            if (bv > best2 || (bv == best2 && bi < idx2)) { best2 = bv; idx2 = bi; }
        }

        // attr: smooth-l1 (beta=1) vs g[idx1]
        float ax0 = gs[idx1], ay0 = gs[512 + idx1];
        float ax1 = gs[1024 + idx1], ay1 = gs[1536 + idx1];
        float d;
        d = fabsf(px0 - ax0); s += (d < 1.0f) ? 0.5f * d * d : d - 0.5f;
        d = fabsf(py0 - ay0); s += (d < 1.0f) ? 0.5f * d * d : d - 0.5f;
        d = fabsf(px1 - ax1); s += (d < 1.0f) ? 0.5f * d * d : d - 0.5f;
        d = fabsf(py1 - ay1); s += (d < 1.0f) ? 0.5f * d * d : d - 0.5f;

        // repgt: IoG (no +1 convention) vs g[idx2]
        float rx0 = gs[idx2], ry0 = gs[512 + idx2];
        float rx1 = gs[1024 + idx2], ry1 = gs[1536 + idx2];
        float lx = fmaxf(px0, rx0), ly = fmaxf(py0, ry0);
        float rx = fminf(px1, rx1), ry = fminf(py1, ry1);
        float w = fmaxf(rx - lx, 0.0f), h = fmaxf(ry - ly, 0.0f);
        float inter = w * h;
        float garea = fabsf(rx1 - rx0) * fabsf(ry1 - ry0);
        float iog = inter / garea;
        if (iog > 0.5f) rep = (iog - 0.5f) / REP_DENOM;
        else            rep = -logf(fmaxf(1.0f - iog, EPSF));

        if (lane == 0) { red[wave] = (double)s; red[4 + wave] = (double)rep; }
    }
    __syncthreads();
    if (t == 0) {
        atomicAdd(&acc[0], red[0] + red[1] + red[2] + red[3]);
        atomicAdd(&acc[1], red[4] + red[5] + red[6] + red[7]);
    }
}

// ---------------------------------------------------------------------------
// repbox: strict upper triangle of NxN proposal IoU -> rep term sum.
// 128x128 tiles, 4 waves x 32 rows, 2 columns per lane (wave spans all 128
// cols). Per row: 5 LDS broadcast reads. Wave-uniform early-out: if no lane's
// pair overlaps, every valid pair contributes the constant -log(1-EPS);
// just count them and multiply once at the end.
// ---------------------------------------------------------------------------
__global__ __launch_bounds__(256) void repbox_kernel(
    const float* __restrict__ p5, double* __restrict__ acc, int N)
{
    int bi = blockIdx.y;  // row tile
    int bj = blockIdx.x;  // col tile
    if (bi > bj) return;

    __shared__ float rows[5 * 128];
    __shared__ double red[4];
    int t = threadIdx.x;
    int rbase = bi * 128, cbase = bj * 128;

    if (t < 128) {
        int rg = rbase + t;
        int rc = (rg < N) ? rg : 0;
        rows[0 * 128 + t] = p5[rc * 5 + 0];
        rows[1 * 128 + t] = p5[rc * 5 + 1];
        rows[2 * 128 + t] = p5[rc * 5 + 2];
        rows[3 * 128 + t] = p5[rc * 5 + 3];
        rows[4 * 128 + t] = p5[rc * 5 + 4];
    }

    int wv = t >> 6, lane = t & 63;
    int j0 = cbase + lane, j1 = cbase + lane + 64;
    int j0c = (j0 < N) ? j0 : 0;
    int j1c = (j1 < N) ? j1 : 0;
    float c0x0 = p5[j0c * 5 + 0], c0y0 = p5[j0c * 5 + 1];
    float c0x1 = p5[j0c * 5 + 2], c0y1 = p5[j0c * 5 + 3], c0a = p5[j0c * 5 + 4];
    float c1x0 = p5[j1c * 5 + 0], c1y0 = p5[j1c * 5 + 1];
    float c1x1 = p5[j1c * 5 + 2], c1y1 = p5[j1c * 5 + 3], c1a = p5[j1c * 5 + 4];
    __syncthreads();

    const float eps_term = -__logf(1.0f - EPSF);
    float sum = 0.0f;
    int cnt = 0;
    int r0 = wv * 32;

    #pragma unroll 4
    for (int rr = 0; rr < 32; ++rr) {
        int r = r0 + rr;
        int ig = rbase + r;
        float rx0 = rows[r], ry0 = rows[128 + r];
        float rx1 = rows[256 + r], ry1 = rows[384 + r], ra = rows[512 + r];

        float w0 = fmaxf(fminf(rx1, c0x1) - fmaxf(rx0, c0x0) + 1.0f, 0.0f);
        float h0 = fmaxf(fminf(ry1, c0y1) - fmaxf(ry0, c0y0) + 1.0f, 0.0f);
        float ov0 = w0 * h0;
        float w1 = fmaxf(fminf(rx1, c1x1) - fmaxf(rx0, c1x0) + 1.0f, 0.0f);
        float h1 = fmaxf(fminf(ry1, c1y1) - fmaxf(ry0, c1y0) + 1.0f, 0.0f);
        float ov1 = w1 * h1;

        bool valid0 = (j0 > ig) && (j0 < N) && (ig < N);
        bool valid1 = (j1 > ig) && (j1 < N) && (ig < N);

        if (__any(fmaxf(ov0, ov1) > 0.0f)) {
            float d0 = fmaxf(ra + c0a - ov0, EPSF);
            float v0 = fminf(fmaxf(ov0 * __builtin_amdgcn_rcpf(d0), EPSF), 1.0f);
            float t0 = (v0 > 0.5f) ? (v0 - 0.5f) * (1.0f / REP_DENOM)
                                   : -__logf(fmaxf(1.0f - v0, EPSF));
            if (valid0) sum += t0;
            float d1 = fmaxf(ra + c1a - ov1, EPSF);
            float v1 = fminf(fmaxf(ov1 * __builtin_amdgcn_rcpf(d1), EPSF), 1.0f);
            float t1 = (v1 > 0.5f) ? (v1 - 0.5f) * (1.0f / REP_DENOM)
                                   : -__logf(fmaxf(1.0f - v1, EPSF));
            if (valid1) sum += t1;
        } else {
            cnt += (valid0 ? 1 : 0) + (valid1 ? 1 : 0);
        }
    }
    sum += eps_term * (float)cnt;

    for (int off = 32; off > 0; off >>= 1) sum += __shfl_down(sum, off);
    if (lane == 0) red[wv] = (double)sum;
    __syncthreads();
    if (t == 0) atomicAdd(&acc[2], red[0] + red[1] + red[2] + red[3]);
}

__global__ void finalize_kernel(const double* __restrict__ acc,
                                float* __restrict__ out, int N, long long cnt)
{
    double attr   = acc[0] / (double)N;
    double repgt  = acc[1] / (double)N;
    double repbox = acc[2] / (double)cnt;
    out[0] = (float)(attr + 0.5 * repgt + 0.5 * repbox);
}

extern "C" void kernel_launch(void* const* d_in, const int* in_sizes, int n_in,
                              void* d_out, int out_size, void* d_ws, size_t ws_size,
                              hipStream_t stream) {
    const float* gt  = (const float*)d_in[0];
    const float* pre = (const float*)d_in[1];
    int M = in_sizes[0] / 4;   // 512
    int N = in_sizes[1] / 4;   // 8192

    char* ws = (char*)d_ws;
    double* acc = (double*)ws;
    float* g5 = (float*)(ws + 256);
    size_t g5_bytes = ((size_t)M * 5 * sizeof(float) + 255) / 256 * 256;
    float* p5 = (float*)(ws + 256 + g5_bytes);
    float* out = (float*)d_out;

    int nb = (N + 255) / 256;
    prep_kernel<<<nb, 256, 0, stream>>>(gt, pre, g5, p5, acc, M, N);

    int nblk = (N + 3) / 4;   // one wave per prediction, 4 per block
    attr_repgt_kernel<<<nblk, 256, 0, stream>>>(g5, p5, acc, M, N);

    int nt = (N + 127) / 128;
    dim3 gb(nt, nt);
    repbox_kernel<<<gb, 256, 0, stream>>>(p5, acc, N);

    long long cnt = (long long)N * (N - 1) / 2;
    finalize_kernel<<<1, 1, 0, stream>>>(acc, out, N, cnt);
}

// Round 3
// 75.684 us; speedup vs baseline: 2.6701x; 1.4150x over previous
//
#include <hip/hip_runtime.h>
#include <math.h>

#define EPSF 1e-7f
// 1 - SIGMA - ln(1 - SIGMA) with SIGMA = 0.5
#define REP_DENOM 1.19314718055994530942f

__device__ __forceinline__ float iou_pp(float ax0, float ay0, float ax1, float ay1, float aarea,
                                        float bx0, float by0, float bx1, float by1, float barea) {
    float lx = fmaxf(ax0, bx0), ly = fmaxf(ay0, by0);
    float rx = fminf(ax1, bx1), ry = fminf(ay1, by1);
    float w = fmaxf(rx - lx + 1.0f, 0.0f);
    float h = fmaxf(ry - ly + 1.0f, 0.0f);
    float ov = w * h;
    float denom = fmaxf(aarea + barea - ov, EPSF);
    float v = ov / denom;   // exact division: argmax tie behavior must match ref
    return fminf(fmaxf(v, EPSF), 1.0f);
}

// ---------------------------------------------------------------------------
// prep: xywh -> xyxy; gt stored SoA [5][M] (x0,y0,x1,y1,area+1conv);
// pre stored AoS [N][5].
// ---------------------------------------------------------------------------
__global__ __launch_bounds__(256) void prep_kernel(
    const float* __restrict__ gt, const float* __restrict__ pre,
    float* __restrict__ g5, float* __restrict__ p5, int M, int N)
{
    int i = blockIdx.x * 256 + threadIdx.x;
    if (i < M) {
        float x = gt[i * 4 + 0], y = gt[i * 4 + 1], w = gt[i * 4 + 2], h = gt[i * 4 + 3];
        float x0 = x - w / 2.0f, y0 = y - h / 2.0f;
        float x1 = x + w / 2.0f, y1 = y + h / 2.0f;
        g5[0 * M + i] = x0;
        g5[1 * M + i] = y0;
        g5[2 * M + i] = x1;
        g5[3 * M + i] = y1;
        g5[4 * M + i] = (x1 - x0 + 1.0f) * (y1 - y0 + 1.0f);
    }
    if (i < N) {
        float x = pre[i * 4 + 0], y = pre[i * 4 + 1], w = pre[i * 4 + 2], h = pre[i * 4 + 3];
        float x0 = x - w / 2.0f, y0 = y - h / 2.0f;
        float x1 = x + w / 2.0f, y1 = y + h / 2.0f;
        p5[i * 5 + 0] = x0;
        p5[i * 5 + 1] = y0;
        p5[i * 5 + 2] = x1;
        p5[i * 5 + 3] = y1;
        p5[i * 5 + 4] = (x1 - x0 + 1.0f) * (y1 - y0 + 1.0f);
    }
}

// ---------------------------------------------------------------------------
// attr + repgt: ONE WAVE per prediction (4 waves / 256-thread block).
// Butterfly argmax with (value, min index) tie-break == jnp.argmax.
// NO atomics: per-block partials -> ws slots, summed by finalize.
// ---------------------------------------------------------------------------
__global__ __launch_bounds__(256) void attr_repgt_kernel(
    const float* __restrict__ g5, const float* __restrict__ p5,
    double* __restrict__ attrP, double* __restrict__ repgtP, int M, int N)
{
    __shared__ float gs[5 * 512];
    __shared__ double red[8];
    int t = threadIdx.x;
    for (int k = t; k < 5 * M; k += 256) {
        int c = k / M, m = k - c * M;
        gs[c * 512 + m] = g5[k];
    }
    if (t < 8) red[t] = 0.0;
    __syncthreads();

    int wave = t >> 6, lane = t & 63;
    int n = blockIdx.x * 4 + wave;
    if (n < N) {
        float px0 = p5[n * 5 + 0], py0 = p5[n * 5 + 1];
        float px1 = p5[n * 5 + 2], py1 = p5[n * 5 + 3];
        float pa  = p5[n * 5 + 4];

        float best1 = -1.0f; int idx1 = 0;
        for (int m = lane; m < M; m += 64) {
            float v = iou_pp(gs[m], gs[512 + m], gs[1024 + m], gs[1536 + m], gs[2048 + m],
                             px0, py0, px1, py1, pa);
            if (v > best1) { best1 = v; idx1 = m; }
        }
        for (int off = 32; off > 0; off >>= 1) {
            float bv = __shfl_xor(best1, off);
            int   bi = __shfl_xor(idx1, off);
            if (bv > best1 || (bv == best1 && bi < idx1)) { best1 = bv; idx1 = bi; }
        }

        float best2 = -1.0f; int idx2 = 0;
        for (int m = lane; m < M; m += 64) {
            if (m == idx1) continue;
            float v = iou_pp(gs[m], gs[512 + m], gs[1024 + m], gs[1536 + m], gs[2048 + m],
                             px0, py0, px1, py1, pa);
            if (v > best2) { best2 = v; idx2 = m; }
        }
        for (int off = 32; off > 0; off >>= 1) {
            float bv = __shfl_xor(best2, off);
            int   bi = __shfl_xor(idx2, off);
            if (bv > best2 || (bv == best2 && bi < idx2)) { best2 = bv; idx2 = bi; }
        }

        // attr: smooth-l1 (beta=1) vs g[idx1]
        float ax0 = gs[idx1], ay0 = gs[512 + idx1];
        float ax1 = gs[1024 + idx1], ay1 = gs[1536 + idx1];
        float s = 0.0f, d;
        d = fabsf(px0 - ax0); s += (d < 1.0f) ? 0.5f * d * d : d - 0.5f;
        d = fabsf(py0 - ay0); s += (d < 1.0f) ? 0.5f * d * d : d - 0.5f;
        d = fabsf(px1 - ax1); s += (d < 1.0f) ? 0.5f * d * d : d - 0.5f;
        d = fabsf(py1 - ay1); s += (d < 1.0f) ? 0.5f * d * d : d - 0.5f;

        // repgt: IoG (no +1 convention) vs g[idx2]
        float rx0 = gs[idx2], ry0 = gs[512 + idx2];
        float rx1 = gs[1024 + idx2], ry1 = gs[1536 + idx2];
        float lx = fmaxf(px0, rx0), ly = fmaxf(py0, ry0);
        float rx = fminf(px1, rx1), ry = fminf(py1, ry1);
        float w = fmaxf(rx - lx, 0.0f), h = fmaxf(ry - ly, 0.0f);
        float inter = w * h;
        float garea = fabsf(rx1 - rx0) * fabsf(ry1 - ry0);
        float iog = inter / garea;
        float rep;
        if (iog > 0.5f) rep = (iog - 0.5f) / REP_DENOM;
        else            rep = -logf(fmaxf(1.0f - iog, EPSF));

        if (lane == 0) { red[wave] = (double)s; red[4 + wave] = (double)rep; }
    }
    __syncthreads();
    if (t == 0) {
        attrP[blockIdx.x]  = red[0] + red[1] + red[2] + red[3];
        repgtP[blockIdx.x] = red[4] + red[5] + red[6] + red[7];
    }
}

// ---------------------------------------------------------------------------
// repbox: strict upper triangle of NxN proposal IoU -> rep term sum.
// 128x128 tiles, 4 waves x 32 rows, 2 columns per lane. Wave-uniform
// early-out on zero overlap (term is then the constant -log(1-EPS)).
// Per-block partial -> ws slot (lower-tri blocks write 0).
// ---------------------------------------------------------------------------
__global__ __launch_bounds__(256) void repbox_kernel(
    const float* __restrict__ p5, double* __restrict__ boxP, int N)
{
    int bi = blockIdx.y;  // row tile
    int bj = blockIdx.x;  // col tile
    int slot = bi * gridDim.x + bj;
    int t = threadIdx.x;
    if (bi > bj) {
        if (t == 0) boxP[slot] = 0.0;
        return;
    }

    __shared__ float rows[128 * 5];
    __shared__ double red[4];
    int rbase = bi * 128, cbase = bj * 128;

    for (int k = t; k < 128 * 5; k += 256) {
        int rg = rbase + k / 5;
        rows[k] = (rg < N) ? p5[rbase * 5 + k] : 0.0f;
    }

    int wv = t >> 6, lane = t & 63;
    int j0 = cbase + lane, j1 = cbase + lane + 64;
    int j0c = (j0 < N) ? j0 : 0;
    int j1c = (j1 < N) ? j1 : 0;
    float c0x0 = p5[j0c * 5 + 0], c0y0 = p5[j0c * 5 + 1];
    float c0x1 = p5[j0c * 5 + 2], c0y1 = p5[j0c * 5 + 3], c0a = p5[j0c * 5 + 4];
    float c1x0 = p5[j1c * 5 + 0], c1y0 = p5[j1c * 5 + 1];
    float c1x1 = p5[j1c * 5 + 2], c1y1 = p5[j1c * 5 + 3], c1a = p5[j1c * 5 + 4];
    __syncthreads();

    const float eps_term = -__logf(1.0f - EPSF);
    float sum = 0.0f;
    int cnt = 0;
    int r0 = wv * 32;

    #pragma unroll 4
    for (int rr = 0; rr < 32; ++rr) {
        int r = r0 + rr;
        int ig = rbase + r;
        float rx0 = rows[r * 5 + 0], ry0 = rows[r * 5 + 1];
        float rx1 = rows[r * 5 + 2], ry1 = rows[r * 5 + 3], ra = rows[r * 5 + 4];

        float w0 = fmaxf(fminf(rx1, c0x1) - fmaxf(rx0, c0x0) + 1.0f, 0.0f);
        float h0 = fmaxf(fminf(ry1, c0y1) - fmaxf(ry0, c0y0) + 1.0f, 0.0f);
        float ov0 = w0 * h0;
        float w1 = fmaxf(fminf(rx1, c1x1) - fmaxf(rx0, c1x0) + 1.0f, 0.0f);
        float h1 = fmaxf(fminf(ry1, c1y1) - fmaxf(ry0, c1y0) + 1.0f, 0.0f);
        float ov1 = w1 * h1;

        bool valid0 = (j0 > ig) && (j0 < N) && (ig < N);
        bool valid1 = (j1 > ig) && (j1 < N) && (ig < N);

        if (__any(fmaxf(ov0, ov1) > 0.0f)) {
            float d0 = fmaxf(ra + c0a - ov0, EPSF);
            float v0 = fminf(fmaxf(ov0 * __builtin_amdgcn_rcpf(d0), EPSF), 1.0f);
            float t0 = (v0 > 0.5f) ? (v0 - 0.5f) * (1.0f / REP_DENOM)
                                   : -__logf(fmaxf(1.0f - v0, EPSF));
            if (valid0) sum += t0;
            float d1 = fmaxf(ra + c1a - ov1, EPSF);
            float v1 = fminf(fmaxf(ov1 * __builtin_amdgcn_rcpf(d1), EPSF), 1.0f);
            float t1 = (v1 > 0.5f) ? (v1 - 0.5f) * (1.0f / REP_DENOM)
                                   : -__logf(fmaxf(1.0f - v1, EPSF));
            if (valid1) sum += t1;
        } else {
            cnt += (valid0 ? 1 : 0) + (valid1 ? 1 : 0);
        }
    }
    sum += eps_term * (float)cnt;

    for (int off = 32; off > 0; off >>= 1) sum += __shfl_down(sum, off);
    if (lane == 0) red[wv] = (double)sum;
    __syncthreads();
    if (t == 0) boxP[slot] = red[0] + red[1] + red[2] + red[3];
}

// ---------------------------------------------------------------------------
// finalize: one 256-thread block sums the partial arrays (L2-resident).
// ---------------------------------------------------------------------------
__device__ __forceinline__ double block_sum(const double* p, int n, int t,
                                            double* sred) {
    double s = 0.0;
    for (int k = t; k < n; k += 256) s += p[k];
    for (int off = 32; off > 0; off >>= 1) s += __shfl_down(s, off);
    if ((t & 63) == 0) sred[t >> 6] = s;
    __syncthreads();
    double r = sred[0] + sred[1] + sred[2] + sred[3];
    __syncthreads();
    return r;
}

__global__ __launch_bounds__(256) void finalize_kernel(
    const double* __restrict__ attrP, const double* __restrict__ repgtP, int nA,
    const double* __restrict__ boxP, int nB,
    float* __restrict__ out, int N, long long cnt)
{
    __shared__ double sred[4];
    int t = threadIdx.x;
    double attr   = block_sum(attrP, nA, t, sred);
    double repgt  = block_sum(repgtP, nA, t, sred);
    double repbox = block_sum(boxP, nB, t, sred);
    if (t == 0) {
        out[0] = (float)(attr / (double)N + 0.5 * repgt / (double)N
                         + 0.5 * repbox / (double)cnt);
    }
}

extern "C" void kernel_launch(void* const* d_in, const int* in_sizes, int n_in,
                              void* d_out, int out_size, void* d_ws, size_t ws_size,
                              hipStream_t stream) {
    const float* gt  = (const float*)d_in[0];
    const float* pre = (const float*)d_in[1];
    int M = in_sizes[0] / 4;   // 512
    int N = in_sizes[1] / 4;   // 8192

    int nblk_attr = (N + 3) / 4;      // 2048: one wave per prediction
    int nt = (N + 127) / 128;         // 64 tiles per dim
    int nB = nt * nt;

    char* ws = (char*)d_ws;
    size_t off = 0;
    double* attrP  = (double*)(ws + off); off += (size_t)nblk_attr * 8;
    double* repgtP = (double*)(ws + off); off += (size_t)nblk_attr * 8;
    double* boxP   = (double*)(ws + off); off += (size_t)nB * 8;
    float*  g5     = (float*)(ws + off);  off += ((size_t)M * 5 * 4 + 255) / 256 * 256;
    float*  p5     = (float*)(ws + off);
    float*  out    = (float*)d_out;

    int nb = (N + 255) / 256;
    prep_kernel<<<nb, 256, 0, stream>>>(gt, pre, g5, p5, M, N);

    attr_repgt_kernel<<<nblk_attr, 256, 0, stream>>>(g5, p5, attrP, repgtP, M, N);

    dim3 gb(nt, nt);
    repbox_kernel<<<gb, 256, 0, stream>>>(p5, boxP, N);

    long long cnt = (long long)N * (N - 1) / 2;
    finalize_kernel<<<1, 256, 0, stream>>>(attrP, repgtP, nblk_attr, boxP, nB, out, N, cnt);
}

// Round 4
// 59.308 us; speedup vs baseline: 3.4073x; 1.2761x over previous
//
#include <hip/hip_runtime.h>
#include <math.h>

#define EPSF 1e-7f
// 1/(1 - SIGMA - ln(1 - SIGMA)) with SIGMA = 0.5
#define REP_INV (1.0f / 1.19314718055994530942f)

// Box storage: 8 floats per box (32B, float4-aligned):
// [0]=x0 [1]=y0 [2]=x1p(=x1+1) [3]=y1p(=y1+1) [4]=area(+1 conv) [5..7]=pad

// ---------------------------------------------------------------------------
// prep: xywh -> padded xyxy(+1) records for gt and pre.
// ---------------------------------------------------------------------------
__global__ __launch_bounds__(256) void prep_kernel(
    const float* __restrict__ gt, const float* __restrict__ pre,
    float* __restrict__ gB, float* __restrict__ pB, int M, int N)
{
    int i = blockIdx.x * 256 + threadIdx.x;
    if (i < M) {
        float x = gt[i * 4 + 0], y = gt[i * 4 + 1], w = gt[i * 4 + 2], h = gt[i * 4 + 3];
        float x0 = x - w / 2.0f, y0 = y - h / 2.0f;
        float x1p = x + w / 2.0f + 1.0f, y1p = y + h / 2.0f + 1.0f;
        *(float4*)(gB + (size_t)i * 8) = make_float4(x0, y0, x1p, y1p);
        gB[(size_t)i * 8 + 4] = (x1p - x0) * (y1p - y0);
    }
    if (i < N) {
        float x = pre[i * 4 + 0], y = pre[i * 4 + 1], w = pre[i * 4 + 2], h = pre[i * 4 + 3];
        float x0 = x - w / 2.0f, y0 = y - h / 2.0f;
        float x1p = x + w / 2.0f + 1.0f, y1p = y + h / 2.0f + 1.0f;
        *(float4*)(pB + (size_t)i * 8) = make_float4(x0, y0, x1p, y1p);
        pB[(size_t)i * 8 + 4] = (x1p - x0) * (y1p - y0);
    }
}

// ---------------------------------------------------------------------------
// attr + repgt: ONE WAVE per prediction (4 waves / 256-thread block).
// Butterfly argmax, (value, min-index) tie-break == jnp.argmax first-occ.
// rcp-based IoU is safe for ties: all zero-overlap entries clamp to exactly
// EPS, so tie-breaking matches the exact-division reference.
// ---------------------------------------------------------------------------
__global__ __launch_bounds__(256) void attr_repgt_kernel(
    const float* __restrict__ gB, const float* __restrict__ pB,
    double* __restrict__ attrP, double* __restrict__ repgtP, int M, int N)
{
    __shared__ float4 gs4[512];
    __shared__ float  gsA[512];
    __shared__ double red[8];
    int t = threadIdx.x;
    for (int k = t; k < M; k += 256) {
        gs4[k] = *(const float4*)(gB + (size_t)k * 8);
        gsA[k] = gB[(size_t)k * 8 + 4];
    }
    if (t < 8) red[t] = 0.0;
    __syncthreads();

    int wave = t >> 6, lane = t & 63;
    int n = blockIdx.x * 4 + wave;
    if (n < N) {
        float4 p = *(const float4*)(pB + (size_t)n * 8);
        float  pa = pB[(size_t)n * 8 + 4];

        float best1 = -1.0f; int idx1 = 0;
        for (int m = lane; m < M; m += 64) {
            float4 g = gs4[m]; float ga = gsA[m];
            float w = fmaxf(fminf(g.z, p.z) - fmaxf(g.x, p.x), 0.0f);
            float h = fmaxf(fminf(g.w, p.w) - fmaxf(g.y, p.y), 0.0f);
            float ov = w * h;
            float v = ov * __builtin_amdgcn_rcpf(fmaxf(ga + pa - ov, EPSF));
            v = fminf(fmaxf(v, EPSF), 1.0f);
            if (v > best1) { best1 = v; idx1 = m; }
        }
        for (int off = 32; off > 0; off >>= 1) {
            float bv = __shfl_xor(best1, off);
            int   bi = __shfl_xor(idx1, off);
            if (bv > best1 || (bv == best1 && bi < idx1)) { best1 = bv; idx1 = bi; }
        }

        float best2 = -1.0f; int idx2 = 0;
        for (int m = lane; m < M; m += 64) {
            float4 g = gs4[m]; float ga = gsA[m];
            float w = fmaxf(fminf(g.z, p.z) - fmaxf(g.x, p.x), 0.0f);
            float h = fmaxf(fminf(g.w, p.w) - fmaxf(g.y, p.y), 0.0f);
            float ov = w * h;
            float v = ov * __builtin_amdgcn_rcpf(fmaxf(ga + pa - ov, EPSF));
            v = fminf(fmaxf(v, EPSF), 1.0f);
            v = (m == idx1) ? -1.0f : v;   // scatter-zero equivalent
            if (v > best2) { best2 = v; idx2 = m; }
        }
        for (int off = 32; off > 0; off >>= 1) {
            float bv = __shfl_xor(best2, off);
            int   bi = __shfl_xor(idx2, off);
            if (bv > best2 || (bv == best2 && bi < idx2)) { best2 = bv; idx2 = bi; }
        }

        // attr: smooth-l1 (beta=1) vs g[idx1]; (x1p - gx1p) == (x1 - gx1)
        float4 a = gs4[idx1];
        float s = 0.0f, d;
        d = fabsf(p.x - a.x); s += (d < 1.0f) ? 0.5f * d * d : d - 0.5f;
        d = fabsf(p.y - a.y); s += (d < 1.0f) ? 0.5f * d * d : d - 0.5f;
        d = fabsf(p.z - a.z); s += (d < 1.0f) ? 0.5f * d * d : d - 0.5f;
        d = fabsf(p.w - a.w); s += (d < 1.0f) ? 0.5f * d * d : d - 0.5f;

        // repgt: IoG (no +1 convention) vs g[idx2]; raw x1 = x1p - 1
        float4 rg = gs4[idx2];
        float lx = fmaxf(p.x, rg.x), ly = fmaxf(p.y, rg.y);
        float rbx = fminf(p.z, rg.z) - 1.0f, rby = fminf(p.w, rg.w) - 1.0f;
        float w = fmaxf(rbx - lx, 0.0f), h = fmaxf(rby - ly, 0.0f);
        float inter = w * h;
        float garea = fabsf(rg.z - 1.0f - rg.x) * fabsf(rg.w - 1.0f - rg.y);
        float iog = inter / garea;
        float rep;
        if (iog > 0.5f) rep = (iog - 0.5f) * REP_INV;
        else            rep = -logf(fmaxf(1.0f - iog, EPSF));

        if (lane == 0) { red[wave] = (double)s; red[4 + wave] = (double)rep; }
    }
    __syncthreads();
    if (t == 0) {
        attrP[blockIdx.x]  = red[0] + red[1] + red[2] + red[3];
        repgtP[blockIdx.x] = red[4] + red[5] + red[6] + red[7];
    }
}

// ---------------------------------------------------------------------------
// repbox: strict upper triangle of NxN proposal IoU -> rep-term sum.
// 1D grid over upper-tri 128x128 tiles. Interior tiles (bi<bj, in-bounds):
// no predicates at all. Diagonal/edge tiles: masked path.
// Zero-overlap pairs contribute exactly 0 here (true value -log(1-EPS)
// ~= 1e-7 each; total final-scalar error ~5e-8, far below threshold).
// ---------------------------------------------------------------------------
__global__ __launch_bounds__(256) void repbox_kernel(
    const float* __restrict__ pB, double* __restrict__ boxP, int N, int nt)
{
    // decode triangular index s -> (bi, bj), bi <= bj
    int s = blockIdx.x;
    float a = 2.0f * (float)nt + 1.0f;
    int bi = (int)((a - sqrtf(a * a - 8.0f * (float)s)) * 0.5f);
    if (bi < 0) bi = 0;
    if (bi > nt - 1) bi = nt - 1;
    while (bi > 0 && (long long)bi * nt - (long long)bi * (bi - 1) / 2 > s) --bi;
    while ((long long)(bi + 1) * nt - (long long)(bi + 1) * bi / 2 <= s) ++bi;
    long long rowoff = (long long)bi * nt - (long long)bi * (bi - 1) / 2;
    int bj = bi + (int)(s - rowoff);

    __shared__ float4 rows4[128];
    __shared__ float  rowsA[128];
    __shared__ double red[4];
    int t = threadIdx.x;
    int rbase = bi * 128, cbase = bj * 128;

    if (t < 128) {
        int rg = rbase + t;
        int rc = (rg < N) ? rg : 0;
        rows4[t] = *(const float4*)(pB + (size_t)rc * 8);
        rowsA[t] = pB[(size_t)rc * 8 + 4];
    }

    int wv = t >> 6, lane = t & 63;
    int j0 = cbase + lane, j1 = j0 + 64;
    int j0c = (j0 < N) ? j0 : 0;
    int j1c = (j1 < N) ? j1 : 0;
    float4 c0 = *(const float4*)(pB + (size_t)j0c * 8);
    float  c0a = pB[(size_t)j0c * 8 + 4];
    float4 c1 = *(const float4*)(pB + (size_t)j1c * 8);
    float  c1a = pB[(size_t)j1c * 8 + 4];
    __syncthreads();

    float sum = 0.0f;
    int r0 = wv * 32;
    bool interior = (bi < bj) && (rbase + 128 <= N) && (cbase + 128 <= N);

    if (interior) {
        #pragma unroll 4
        for (int rr = 0; rr < 32; ++rr) {
            int r = r0 + rr;
            float4 rb = rows4[r]; float ra = rowsA[r];
            float w0 = fmaxf(fminf(rb.z, c0.z) - fmaxf(rb.x, c0.x), 0.0f);
            float h0 = fmaxf(fminf(rb.w, c0.w) - fmaxf(rb.y, c0.y), 0.0f);
            float ov0 = w0 * h0;
            float w1 = fmaxf(fminf(rb.z, c1.z) - fmaxf(rb.x, c1.x), 0.0f);
            float h1 = fmaxf(fminf(rb.w, c1.w) - fmaxf(rb.y, c1.y), 0.0f);
            float ov1 = w1 * h1;
            if (__any(ov0 + ov1 > 0.0f)) {
                float v0 = ov0 * __builtin_amdgcn_rcpf(ra + c0a - ov0);
                float t0 = (v0 > 0.5f) ? (v0 - 0.5f) * REP_INV
                                       : 0.0f - __logf(fmaxf(1.0f - v0, EPSF));
                float v1 = ov1 * __builtin_amdgcn_rcpf(ra + c1a - ov1);
                float t1 = (v1 > 0.5f) ? (v1 - 0.5f) * REP_INV
                                       : 0.0f - __logf(fmaxf(1.0f - v1, EPSF));
                sum += t0 + t1;
            }
        }
    } else {
        #pragma unroll 4
        for (int rr = 0; rr < 32; ++rr) {
            int r = r0 + rr;
            int ig = rbase + r;
            float4 rb = rows4[r]; float ra = rowsA[r];
            float w0 = fmaxf(fminf(rb.z, c0.z) - fmaxf(rb.x, c0.x), 0.0f);
            float h0 = fmaxf(fminf(rb.w, c0.w) - fmaxf(rb.y, c0.y), 0.0f);
            float ov0 = w0 * h0;
            float w1 = fmaxf(fminf(rb.z, c1.z) - fmaxf(rb.x, c1.x), 0.0f);
            float h1 = fmaxf(fminf(rb.w, c1.w) - fmaxf(rb.y, c1.y), 0.0f);
            float ov1 = w1 * h1;
            bool valid0 = (j0 > ig) && (j0 < N) && (ig < N);
            bool valid1 = (j1 > ig) && (j1 < N) && (ig < N);
            if (__any(ov0 + ov1 > 0.0f)) {
                float v0 = ov0 * __builtin_amdgcn_rcpf(ra + c0a - ov0);
                float t0 = (v0 > 0.5f) ? (v0 - 0.5f) * REP_INV
                                       : 0.0f - __logf(fmaxf(1.0f - v0, EPSF));
                float v1 = ov1 * __builtin_amdgcn_rcpf(ra + c1a - ov1);
                float t1 = (v1 > 0.5f) ? (v1 - 0.5f) * REP_INV
                                       : 0.0f - __logf(fmaxf(1.0f - v1, EPSF));
                if (valid0) sum += t0;
                if (valid1) sum += t1;
            }
        }
    }

    for (int off = 32; off > 0; off >>= 1) sum += __shfl_down(sum, off);
    if (lane == 0) red[wv] = (double)sum;
    __syncthreads();
    if (t == 0) boxP[blockIdx.x] = red[0] + red[1] + red[2] + red[3];
}

// ---------------------------------------------------------------------------
// finalize: one 256-thread block sums the partial arrays (L2-resident).
// ---------------------------------------------------------------------------
__device__ __forceinline__ double block_sum(const double* p, int n, int t,
                                            double* sred) {
    double s = 0.0;
    for (int k = t; k < n; k += 256) s += p[k];
    for (int off = 32; off > 0; off >>= 1) s += __shfl_down(s, off);
    if ((t & 63) == 0) sred[t >> 6] = s;
    __syncthreads();
    double r = sred[0] + sred[1] + sred[2] + sred[3];
    __syncthreads();
    return r;
}

__global__ __launch_bounds__(256) void finalize_kernel(
    const double* __restrict__ attrP, const double* __restrict__ repgtP, int nA,
    const double* __restrict__ boxP, int nB,
    float* __restrict__ out, int N, long long cnt)
{
    __shared__ double sred[4];
    int t = threadIdx.x;
    double attr   = block_sum(attrP, nA, t, sred);
    double repgt  = block_sum(repgtP, nA, t, sred);
    double repbox = block_sum(boxP, nB, t, sred);
    if (t == 0) {
        out[0] = (float)(attr / (double)N + 0.5 * repgt / (double)N
                         + 0.5 * repbox / (double)cnt);
    }
}

extern "C" void kernel_launch(void* const* d_in, const int* in_sizes, int n_in,
                              void* d_out, int out_size, void* d_ws, size_t ws_size,
                              hipStream_t stream) {
    const float* gt  = (const float*)d_in[0];
    const float* pre = (const float*)d_in[1];
    int M = in_sizes[0] / 4;   // 512
    int N = in_sizes[1] / 4;   // 8192

    int nblk_attr = (N + 3) / 4;          // 2048: one wave per prediction
    int nt = (N + 127) / 128;             // 64 row/col tiles
    int nTri = nt * (nt + 1) / 2;         // 2080 upper-tri tiles

    char* ws = (char*)d_ws;
    size_t off = 0;
    double* attrP  = (double*)(ws + off); off += ((size_t)nblk_attr * 8 + 255) / 256 * 256;
    double* repgtP = (double*)(ws + off); off += ((size_t)nblk_attr * 8 + 255) / 256 * 256;
    double* boxP   = (double*)(ws + off); off += ((size_t)nTri * 8 + 255) / 256 * 256;
    float*  gB     = (float*)(ws + off);  off += ((size_t)M * 8 * 4 + 255) / 256 * 256;
    float*  pB     = (float*)(ws + off);
    float*  out    = (float*)d_out;

    int mx = (M > N) ? M : N;
    prep_kernel<<<(mx + 255) / 256, 256, 0, stream>>>(gt, pre, gB, pB, M, N);

    attr_repgt_kernel<<<nblk_attr, 256, 0, stream>>>(gB, pB, attrP, repgtP, M, N);

    repbox_kernel<<<nTri, 256, 0, stream>>>(pB, boxP, N, nt);

    long long cnt = (long long)N * (N - 1) / 2;
    finalize_kernel<<<1, 256, 0, stream>>>(attrP, repgtP, nblk_attr, boxP, nTri, out, N, cnt);
}